// Round 14
// baseline (230.369 us; speedup 1.0000x reference)
//
#include <hip/hip_runtime.h>
#include <hip/hip_bf16.h>
#include <cstdint>
#include <cstddef>

typedef unsigned short u16;
typedef unsigned char u8;
using f32x4 = __attribute__((ext_vector_type(4))) float;
using s16x8 = __attribute__((ext_vector_type(8))) short;
using s64x2 = __attribute__((ext_vector_type(2))) long;

#define NN 2048      // nodes
#define BB 32        // batch
#define CC 66        // input_size (2 + 64)
#define JREAL 2112   // BB*CC real j-rows
#define JR 2176      // padded
#define KF 352       // 5*66 = 330 padded to 11*32
#define SROWS 65536  // BB*NN

// k-paired packed layout within each 64-byte K-block:
//   new[16*q + 8*h + b] = old[8*q + 32*h + b],  q:0..3, h:0..1, b:0..7
// NOTE: even/odd k-pairs stay ADJACENT under kperm (b=k&7 increments within
// an octet), enabling paired 2-byte stores of fp8 pairs.
__device__ __forceinline__ int kperm(int k6) {
  return 16 * ((k6 >> 3) & 3) + 8 * (k6 >> 5) + (k6 & 7);
}

__device__ __forceinline__ float bf2f(u16 u) {
  union { uint32_t i; float f; } v; v.i = ((uint32_t)u) << 16; return v.f;
}
__device__ __forceinline__ u16 f2bf(float f) {
  union { float f; uint32_t i; } v; v.f = f;
  uint32_t x = v.i;
  x += 0x7fffu + ((x >> 16) & 1u);   // RNE
  return (u16)(x >> 16);
}
// f32 -> OCP e4m3fn, RNE, saturate to 448.
__device__ __forceinline__ u8 f2e4m3(float x) {
  union { float f; uint32_t i; } v; v.f = x;
  uint32_t s = (v.i >> 24) & 0x80u;
  float a = fabsf(x);
  if (a >= 464.0f) return (u8)(s | 0x7Eu);
  if (a < 0.015625f) {
    int q = (int)rintf(a * 512.0f);
    return (u8)(s | (uint32_t)q);
  }
  union { float f; uint32_t i; } u; u.f = a;
  uint32_t lsb = (u.i >> 20) & 1u;
  u.i += 0x0007FFFFu + lsb;
  int e = (int)(u.i >> 23) - 127;
  uint32_t m = (u.i >> 20) & 7u;
  return (u8)(s | ((uint32_t)(e + 7) << 3) | m);
}

__device__ __forceinline__ void async_cp16(const u8* g, u8* l) {
  __builtin_amdgcn_global_load_lds(
      (const __attribute__((address_space(1))) unsigned int*)g,
      (__attribute__((address_space(3))) unsigned int*)l, 16, 0, 0);
}
__device__ __forceinline__ void async_cp16u(const u16* g, u16* l) {
  __builtin_amdgcn_global_load_lds(
      (const __attribute__((address_space(1))) unsigned int*)g,
      (__attribute__((address_space(3))) unsigned int*)l, 16, 0, 0);
}

// ---------------------------------------------------------------------------
// gemm_f8 (r16 K-loop — measured 65.7us, MfmaUtil 52, FETCH 32MB):
// C tile 128(M=j) x 256(N=n) = A * B^T, fp8 e4m3, k-paired layout, BK=64,
// 8 waves 64x64, conflict-free single-b128 fragment reads.  3-slot ring
// (76.8 KB, 2 blocks/CU), prefetch 2, 4 phases/K-tile each {ds_read || 1
// gload -> barrier -> lgkmcnt(0) -> setprio(1) -> 8(+2 sliver) MFMA ->
// setprio(0) -> barrier}; counted vmcnt(3)/(4) once per K-tile at phase 3.
// (r17 2x16-merge and r18 256^2 both regressed — this is the local optimum.)
// Sliver: leftover 64 j-rows folded into mb<4 blocks.
// EPI 5 (r23/r24, bank-conflict-free measured 0): single-pass scatter, tl
// stride 132 u16 so 4 contiguous j-slots per (mi,ni) store as ONE ushort4;
// sliver scatter paired to u32.
// ---------------------------------------------------------------------------
template <int EPI>
__global__ __launch_bounds__(512, 2) void gemm_f8(
    const u8* __restrict__ A0, const u8* __restrict__ A1,
    const u8* __restrict__ A2, const u8* __restrict__ A3,
    const u8* __restrict__ B0, const u8* __restrict__ B1,
    const u8* __restrict__ B2, const u8* __restrict__ B3,
    void* __restrict__ C0, void* __restrict__ C1,
    void* __restrict__ C2, void* __restrict__ C3,
    int K, int lda, int ldb, int ldout, int mlimit)
{
  // slot: A 128x64B (8KB) + B 256x64B (16KB) + A-sliver 16x64B (1KB) = 25600
  __shared__ u8 lds[3 * 25600];

  const int gx = gridDim.x, gy = gridDim.y;
  const int nwg = gx * gy * gridDim.z;
  const int orig = blockIdx.x + gx * (blockIdx.y + gy * blockIdx.z);
  const int cpx = nwg >> 3;
  const int swz = (orig & 7) * cpx + (orig >> 3);
  const int mb = swz % gx;
  const int t1 = swz / gx;
  const int nb = t1 % gy;
  const int zb = t1 / gy;

  const u8* A = (zb == 0) ? A0 : (zb == 1) ? A1 : (zb == 2) ? A2 : A3;
  const u8* B = (zb == 0) ? B0 : (zb == 1) ? B1 : (zb == 2) ? B2 : B3;
  void* Cv    = (zb == 0) ? C0 : (zb == 1) ? C1 : (zb == 2) ? C2 : C3;

  const int tid = threadIdx.x;
  const int wid = tid >> 6;
  const int lane = tid & 63;
  const int m0 = mb * 128;
  const int n0 = nb * 256;
  const int wm = (wid >> 2) * 64;   // 2 wave-rows
  const int wn = (wid & 3) * 64;    // 4 wave-cols

  // sliver of leftover rows j in [2048,2112): blocks mb<4 take 16 rows each
  const bool xtra = (EPI == 5) && (mb < 4);
  const int xrow0 = 2048 + mb * 16;
  const bool xw = xtra && (wid == 0);   // staging wave for the sliver
  const bool xm = xtra && (wid < 4);    // compute waves (wm==0)

  // ---- staging: 16B/lane; source granule pre-swizzled (LDS dest linear) ----
  const int srow = wid * 16 + (lane >> 2);                  // 0..127 per pass
  const int sk   = ((lane & 3) ^ ((lane >> 3) & 3)) * 16;   // swizzled granule
  const u8* gA = A + (size_t)(m0 + srow) * lda + sk;
  const u8* gB = B + (size_t)(n0 + srow) * ldb + sk;        // +128*ldb pass 1
  const u8* gAx = A + (size_t)(xrow0 + (lane >> 2)) * lda + sk;  // 16 rows
  u8* ldsA  = &lds[wid * 1024];           // + slot*25600
  u8* ldsB0 = &lds[8192 + wid * 1024];
  u8* ldsB1 = &lds[16384 + wid * 1024];
  u8* ldsAx = &lds[24576];                // 1KB sliver region (wave 0 writes)

  // ---- ds_read: one b128 per fragment-pair, granule (hi ^ rq) ----
  const int r16 = lane & 15;
  const int hi = lane >> 4;
  const int rq = (r16 >> 1) & 3;
  const int goff = (hi ^ rq) * 16;
  const int abase = (wm + r16) * 64 + goff;           // + mi*1024
  const int bbase = 8192 + (wn + r16) * 64 + goff;    // + ni*1024
  const int xbase = 24576 + r16 * 64 + goff;          // sliver fragment

  f32x4 acc[4][4] = {};
  f32x4 accx[4] = {};
  const int nt = K >> 6;   // K-tiles of 64

#define STAGE_ALL(T_, SO_) { const int k0_ = (T_) * 64;                      \
    async_cp16(gA + k0_, ldsA + (SO_));                                      \
    async_cp16(gB + k0_, ldsB0 + (SO_));                                     \
    async_cp16(gB + (size_t)128 * ldb + k0_, ldsB1 + (SO_));                 \
    if (xw) async_cp16(gAx + k0_, ldsAx + (SO_)); }

  STAGE_ALL(0, 0);
  STAGE_ALL(1, 25600);
  // tile 0 landed (wave-local count: wave 0 of sliver blocks has 4/stage)
  if (xw) { asm volatile("s_waitcnt vmcnt(4)" ::: "memory"); }
  else    { asm volatile("s_waitcnt vmcnt(3)" ::: "memory"); }
  __builtin_amdgcn_s_barrier();

  int scur = 0;                 // slot of tile t
  for (int t = 0; t < nt; ++t) {
    const int soff = scur * 25600;
    const bool more = (t + 2) < nt;
    int sst = scur + 2; if (sst >= 3) sst -= 3;
    const int so2 = sst * 25600;
    const int k2 = (t + 2) * 64;

    s64x2 af[4], bq, axf;

    // ---- phase 0: af[0..3] + bq(n=0) (+ sliver axf) || stage A(t+2) ----
#pragma unroll
    for (int mi = 0; mi < 4; ++mi)
      af[mi] = *(const s64x2*)&lds[soff + abase + mi * 1024];
    bq = *(const s64x2*)&lds[soff + bbase];
    if (xm) axf = *(const s64x2*)&lds[soff + xbase];
    if (more) async_cp16(gA + k2, ldsA + so2);
    __builtin_amdgcn_s_barrier();
    asm volatile("s_waitcnt lgkmcnt(0)" ::: "memory");
    __builtin_amdgcn_s_setprio(1);
#pragma unroll
    for (int h = 0; h < 2; ++h) {
#pragma unroll
      for (int mi = 0; mi < 4; ++mi)
        acc[mi][0] = __builtin_amdgcn_mfma_f32_16x16x32_fp8_fp8(
            af[mi][h], bq[h], acc[mi][0], 0, 0, 0);
      if (xm) accx[0] = __builtin_amdgcn_mfma_f32_16x16x32_fp8_fp8(
            axf[h], bq[h], accx[0], 0, 0, 0);
    }
    __builtin_amdgcn_s_setprio(0);
    __builtin_amdgcn_s_barrier();

    // ---- phase 1: bq(n=1) || stage B0(t+2) ----
    bq = *(const s64x2*)&lds[soff + bbase + 1024];
    if (more) async_cp16(gB + k2, ldsB0 + so2);
    __builtin_amdgcn_s_barrier();
    asm volatile("s_waitcnt lgkmcnt(0)" ::: "memory");
    __builtin_amdgcn_s_setprio(1);
#pragma unroll
    for (int h = 0; h < 2; ++h) {
#pragma unroll
      for (int mi = 0; mi < 4; ++mi)
        acc[mi][1] = __builtin_amdgcn_mfma_f32_16x16x32_fp8_fp8(
            af[mi][h], bq[h], acc[mi][1], 0, 0, 0);
      if (xm) accx[1] = __builtin_amdgcn_mfma_f32_16x16x32_fp8_fp8(
            axf[h], bq[h], accx[1], 0, 0, 0);
    }
    __builtin_amdgcn_s_setprio(0);
    __builtin_amdgcn_s_barrier();

    // ---- phase 2: bq(n=2) || stage B1(t+2) ----
    bq = *(const s64x2*)&lds[soff + bbase + 2048];
    if (more) async_cp16(gB + (size_t)128 * ldb + k2, ldsB1 + so2);
    __builtin_amdgcn_s_barrier();
    asm volatile("s_waitcnt lgkmcnt(0)" ::: "memory");
    __builtin_amdgcn_s_setprio(1);
#pragma unroll
    for (int h = 0; h < 2; ++h) {
#pragma unroll
      for (int mi = 0; mi < 4; ++mi)
        acc[mi][2] = __builtin_amdgcn_mfma_f32_16x16x32_fp8_fp8(
            af[mi][h], bq[h], acc[mi][2], 0, 0, 0);
      if (xm) accx[2] = __builtin_amdgcn_mfma_f32_16x16x32_fp8_fp8(
            axf[h], bq[h], accx[2], 0, 0, 0);
    }
    __builtin_amdgcn_s_setprio(0);
    __builtin_amdgcn_s_barrier();

    // ---- phase 3: bq(n=3) || stage sliver(t+2); counted vmcnt ----
    bq = *(const s64x2*)&lds[soff + bbase + 3072];
    if (more && xw) async_cp16(gAx + k2, ldsAx + so2);
    __builtin_amdgcn_s_barrier();
    asm volatile("s_waitcnt lgkmcnt(0)" ::: "memory");
    __builtin_amdgcn_s_setprio(1);
#pragma unroll
    for (int h = 0; h < 2; ++h) {
#pragma unroll
      for (int mi = 0; mi < 4; ++mi)
        acc[mi][3] = __builtin_amdgcn_mfma_f32_16x16x32_fp8_fp8(
            af[mi][h], bq[h], acc[mi][3], 0, 0, 0);
      if (xm) accx[3] = __builtin_amdgcn_mfma_f32_16x16x32_fp8_fp8(
            axf[h], bq[h], accx[3], 0, 0, 0);
    }
    __builtin_amdgcn_s_setprio(0);
    if (more) {
      if (xw) { asm volatile("s_waitcnt vmcnt(4)" ::: "memory"); }
      else    { asm volatile("s_waitcnt vmcnt(3)" ::: "memory"); }
    } else {
      asm volatile("s_waitcnt vmcnt(0)" ::: "memory");
    }
    __builtin_amdgcn_s_barrier();
    scur = (scur + 1 == 3) ? 0 : scur + 1;
  }
#undef STAGE_ALL

  const int lr = (lane >> 4) * 4;
  const int lc = lane & 15;

  if (EPI == 5) {
    // fused xcat scatter: acc[j][n] -> xcat[(b*NN+n)][ (zb+1)*66 + c ]
    // single-pass: tl = 256 np x 128 j, stride 132 u16 (67.6 KB <= 76.8 KB;
    // 264B row pitch is 8B-aligned -> ushort4 stores)
    u16* tl = (u16*)lds;
    u16* xc = (u16*)Cv;
    // sliver epilogue: direct scatter, j in [xrow0,xrow0+16) => b=31,
    // c=j-2046; paired u32 stores (all index terms even, 4B-aligned).
    if (xm) {
#pragma unroll
      for (int ni = 0; ni < 4; ++ni) {
        const int ng = n0 + wn + ni * 16 + lc;
        const size_t base = ((size_t)31 * NN + ng) * KF +
                            (size_t)(zb + 1) * CC + (xrow0 + lr - 2046);
        const uint32_t w0 = (uint32_t)f2bf(accx[ni][0] * 0.00390625f) |
                            ((uint32_t)f2bf(accx[ni][1] * 0.00390625f) << 16);
        const uint32_t w1 = (uint32_t)f2bf(accx[ni][2] * 0.00390625f) |
                            ((uint32_t)f2bf(accx[ni][3] * 0.00390625f) << 16);
        *reinterpret_cast<uint32_t*>(&xc[base])     = w0;
        *reinterpret_cast<uint32_t*>(&xc[base + 2]) = w1;
      }
    }
    // all waves write their full acc once (K-loop's final barrier already
    // guarantees ring-LDS reads are done); 4 contiguous j per ushort4
#pragma unroll
    for (int mi = 0; mi < 4; ++mi)
#pragma unroll
      for (int ni = 0; ni < 4; ++ni) {
        const int np = wn + ni * 16 + lc;        // 0..255
        const int j = wm + mi * 16 + lr;         // multiple of 4
        ushort4 w4;
        w4.x = f2bf(acc[mi][ni][0] * 0.00390625f);
        w4.y = f2bf(acc[mi][ni][1] * 0.00390625f);
        w4.z = f2bf(acc[mi][ni][2] * 0.00390625f);
        w4.w = f2bf(acc[mi][ni][3] * 0.00390625f);
        *reinterpret_cast<ushort4*>(&tl[np * 132 + j]) = w4;
      }
    __syncthreads();
    // write out: paired u32 stores — thread handles j-pair (2k, 2k+1);
    // pairs never straddle a 66-boundary (66 even), all indices u32-aligned.
    for (int p = 0; p < 32; ++p) {
      const int idx = p * 512 + tid;      // 0..16383
      const int jj = (idx & 63) * 2;      // 64 j-pairs
      const int np = idx >> 6;            // 0..255
      const int j = m0 + jj;              // < 2048 (sliver covers the rest)
      const int b = j / CC;
      const int c = j - b * CC;
      const int ng = n0 + np;
      *reinterpret_cast<uint32_t*>(
          &xc[((size_t)b * NN + ng) * KF + (size_t)(zb + 1) * CC + c]) =
          *reinterpret_cast<const uint32_t*>(&tl[np * 132 + jj]);
    }
  } else {
#pragma unroll
    for (int mi = 0; mi < 4; ++mi)
#pragma unroll
      for (int ni = 0; ni < 4; ++ni) {
        const int colg = n0 + wn + ni * 16 + lc;
#pragma unroll
        for (int r = 0; r < 4; ++r) {
          const int rowg = m0 + wm + mi * 16 + lr + r;
          if (rowg < mlimit) {
            if (EPI == 0) {
              ((u16*)Cv)[(size_t)rowg * ldout + colg] =
                  f2bf(acc[mi][ni][r] * 0.00390625f);          // * 2^-8
            } else {
              float v = acc[mi][ni][r] * 0.0078125f -          // * 2^-7
                        ((rowg == colg) ? 256.0f : 0.0f);
              const int cpk = (colg & ~63) + kperm(colg & 63);
              ((u8*)Cv)[(size_t)rowg * ldout + cpk] = f2e4m3(v);
            }
          }
        }
      }
  }
}

// ---------------------------------------------------------------------------
// gemm_f8T: T = 2*S*S - I, tile 128 x 128 -> grid 16x16x2 = 512 blocks
// (2/CU).  8 waves, wave-tile 64x32 (acc[4][2]), BK=64, 3-slot ring 48 KB.
// r28: 2-PHASE K-loop (r17's port, now isolated; r17 ledger residual says
// ~-2us): phase A {af[0..3]+bq(ni=0) || stage A -> barrier -> lgkm -> 8
// MFMA}; phase B {bq(ni=1) || stage B -> 8 MFMA -> counted vmcnt(2)}.
// Out: fp8 = acc*2^-7 - 256*I at k-permuted col (x2^8 scale kept).
// S0t/S1t live in cd's space (NOT xcat) — pack #1 can't race this kernel.
// ---------------------------------------------------------------------------
__global__ __launch_bounds__(512, 2) void gemm_f8T(
    const u8* __restrict__ A0, const u8* __restrict__ A1,
    const u8* __restrict__ B0, const u8* __restrict__ B1,
    u8* __restrict__ C0, u8* __restrict__ C1,
    int K, int lda, int ldb, int ldout)
{
  __shared__ u8 lds[3 * 16384];   // slot: A 128x64B (8KB) + B 128x64B (8KB)

  const int gx = gridDim.x, gy = gridDim.y;
  const int nwg = gx * gy * gridDim.z;
  const int orig = blockIdx.x + gx * (blockIdx.y + gy * blockIdx.z);
  const int cpx = nwg >> 3;
  const int swz = (orig & 7) * cpx + (orig >> 3);
  const int mb = swz % gx;
  const int t1 = swz / gx;
  const int nb = t1 % gy;
  const int zb = t1 / gy;

  const u8* A = zb ? A1 : A0;
  const u8* B = zb ? B1 : B0;
  u8* C = zb ? C1 : C0;

  const int tid = threadIdx.x;
  const int wid = tid >> 6;
  const int lane = tid & 63;
  const int m0 = mb * 128;
  const int n0 = nb * 128;
  const int wm = (wid >> 2) * 64;   // 2 wave-rows (64)
  const int wn = (wid & 3) * 32;    // 4 wave-cols (32)

  const int srow = wid * 16 + (lane >> 2);                  // 0..127
  const int sk   = ((lane & 3) ^ ((lane >> 3) & 3)) * 16;   // swizzled granule
  const u8* gA = A + (size_t)(m0 + srow) * lda + sk;
  const u8* gB = B + (size_t)(n0 + srow) * ldb + sk;
  u8* ldsA = &lds[wid * 1024];            // + slot*16384
  u8* ldsB = &lds[8192 + wid * 1024];

  const int r16 = lane & 15;
  const int hi = lane >> 4;
  const int rq = (r16 >> 1) & 3;
  const int goff = (hi ^ rq) * 16;
  const int abase = (wm + r16) * 64 + goff;           // + mi*1024, mi 0..3
  const int bbase = 8192 + (wn + r16) * 64 + goff;    // + ni*1024, ni 0..1

  f32x4 acc[4][2] = {};
  const int nt = K >> 6;

#define STAGE(T_, SO_) { const int k0_ = (T_) * 64;                          \
    async_cp16(gA + k0_, ldsA + (SO_));                                      \
    async_cp16(gB + k0_, ldsB + (SO_)); }

  STAGE(0, 0);
  STAGE(1, 16384);
  asm volatile("s_waitcnt vmcnt(2)" ::: "memory");   // tile 0 landed
  __builtin_amdgcn_s_barrier();

  int scur = 0;
  for (int t = 0; t < nt; ++t) {
    const int soff = scur * 16384;
    const bool more = (t + 2) < nt;
    int sst = scur + 2; if (sst >= 3) sst -= 3;
    const int so2 = sst * 16384;
    const int k2 = (t + 2) * 64;

    s64x2 af[4], bq;

    // ---- phase A: af[0..3] + bq(n=0) || stage A(t+2) ----
#pragma unroll
    for (int mi = 0; mi < 4; ++mi)
      af[mi] = *(const s64x2*)&lds[soff + abase + mi * 1024];
    bq = *(const s64x2*)&lds[soff + bbase];
    if (more) async_cp16(gA + k2, ldsA + so2);
    __builtin_amdgcn_s_barrier();
    asm volatile("s_waitcnt lgkmcnt(0)" ::: "memory");
    __builtin_amdgcn_s_setprio(1);
#pragma unroll
    for (int h = 0; h < 2; ++h)
#pragma unroll
      for (int mi = 0; mi < 4; ++mi)
        acc[mi][0] = __builtin_amdgcn_mfma_f32_16x16x32_fp8_fp8(
            af[mi][h], bq[h], acc[mi][0], 0, 0, 0);
    __builtin_amdgcn_s_setprio(0);
    __builtin_amdgcn_s_barrier();

    // ---- phase B: bq(n=1) || stage B(t+2); counted vmcnt ----
    bq = *(const s64x2*)&lds[soff + bbase + 1024];
    if (more) async_cp16(gB + k2, ldsB + so2);
    __builtin_amdgcn_s_barrier();
    asm volatile("s_waitcnt lgkmcnt(0)" ::: "memory");
    __builtin_amdgcn_s_setprio(1);
#pragma unroll
    for (int h = 0; h < 2; ++h)
#pragma unroll
      for (int mi = 0; mi < 4; ++mi)
        acc[mi][1] = __builtin_amdgcn_mfma_f32_16x16x32_fp8_fp8(
            af[mi][h], bq[h], acc[mi][1], 0, 0, 0);
    __builtin_amdgcn_s_setprio(0);
    if (more) { asm volatile("s_waitcnt vmcnt(2)" ::: "memory"); }
    else      { asm volatile("s_waitcnt vmcnt(0)" ::: "memory"); }
    __builtin_amdgcn_s_barrier();
    scur = (scur + 1 == 3) ? 0 : scur + 1;
  }
#undef STAGE

  const int lr = (lane >> 4) * 4;
  const int lc = lane & 15;
#pragma unroll
  for (int mi = 0; mi < 4; ++mi)
#pragma unroll
    for (int ni = 0; ni < 2; ++ni) {
      const int colg = n0 + wn + ni * 16 + lc;
      const int cpk = (colg & ~63) + kperm(colg & 63);
#pragma unroll
      for (int r = 0; r < 4; ++r) {
        const int rowg = m0 + wm + mi * 16 + lr + r;
        float v = acc[mi][ni][r] * 0.0078125f -
                  ((rowg == colg) ? 256.0f : 0.0f);
        C[(size_t)rowg * ldout + cpk] = f2e4m3(v);
      }
    }
}

// ---------------------------------------------------------------------------
// gemm_dense (r16-exact): 128x128 2-barrier bf16 kernel for the dense layers
// (N=128, K=352).  EPI 2: sigmoid(acc+bias); EPI 3: tanh(acc+bias).
// Dedicated streaming kernels (pack_x0/final_k) measured FASTER than fusing
// this epilogue (r19/r20: +9us net; r25 isolated final_k fusion: +6us).
// ---------------------------------------------------------------------------
template <int EPI>
__global__ __launch_bounds__(256) void gemm_dense(
    const u16* __restrict__ A, const u16* __restrict__ B, u16* __restrict__ C,
    const float* __restrict__ bias,
    int K, int lda, int ldb, int ldout, int nstore)
{
  __shared__ u16 At[128 * 32];
  __shared__ u16 Bt[128 * 32];
  const int nwg = gridDim.x;
  const int orig = blockIdx.x;
  const int cpx = nwg >> 3;
  const int swz = (orig & 7) * cpx + (orig >> 3);
  const int mb = swz;

  const int tid = threadIdx.x;
  const int wid = tid >> 6;
  const int lane = tid & 63;
  const int m0 = mb * 128;
  const int wm = (wid >> 1) * 64;
  const int wn = (wid & 1) * 64;
  const int rA = lane >> 2;
  const int kA = ((lane & 3) ^ ((lane >> 3) & 3)) * 8;

  f32x4 acc[4][4] = {};

  const int c0 = wid * 2, c1 = wid * 2 + 1;
  const u16* gA0 = A + (size_t)(m0 + c0 * 16 + rA) * lda + kA;
  const u16* gA1 = A + (size_t)(m0 + c1 * 16 + rA) * lda + kA;
  const u16* gB0 = B + (size_t)(c0 * 16 + rA) * ldb + kA;
  const u16* gB1 = B + (size_t)(c1 * 16 + rA) * ldb + kA;

  for (int k0 = 0; k0 < K; k0 += 32) {
    async_cp16u(gA0 + k0, &At[c0 * 512]);
    async_cp16u(gA1 + k0, &At[c1 * 512]);
    async_cp16u(gB0 + k0, &Bt[c0 * 512]);
    async_cp16u(gB1 + k0, &Bt[c1 * 512]);
    __syncthreads();
    s16x8 af[4], bfr[4];
    const int r16 = lane & 15;
    const int cswz = ((lane >> 4) ^ ((r16 >> 1) & 3)) << 3;
#pragma unroll
    for (int mi = 0; mi < 4; ++mi)
      af[mi] = *(const s16x8*)&At[(wm + mi * 16 + r16) * 32 + cswz];
#pragma unroll
    for (int ni = 0; ni < 4; ++ni)
      bfr[ni] = *(const s16x8*)&Bt[(wn + ni * 16 + r16) * 32 + cswz];
#pragma unroll
    for (int mi = 0; mi < 4; ++mi)
#pragma unroll
      for (int ni = 0; ni < 4; ++ni)
        acc[mi][ni] = __builtin_amdgcn_mfma_f32_16x16x32_bf16(af[mi], bfr[ni], acc[mi][ni], 0, 0, 0);
    __syncthreads();
  }

  const int lr = (lane >> 4) * 4;
  const int lc = lane & 15;
#pragma unroll
  for (int mi = 0; mi < 4; ++mi) {
#pragma unroll
    for (int ni = 0; ni < 4; ++ni) {
      const int colg = wn + ni * 16 + lc;
#pragma unroll
      for (int r = 0; r < 4; ++r) {
        const int rowg = m0 + wm + mi * 16 + lr + r;
        float v = acc[mi][ni][r];
        if (EPI == 2) { v += bias[colg]; v = 1.0f / (1.0f + __expf(-v)); }
        if (EPI == 3) { v += bias[colg]; v = tanhf(v); }
        if (colg < nstore)
          C[(size_t)rowg * ldout + colg] = f2bf(v);
      }
    }
  }
}

// ---------------------------------------------------------------------------
// prep (r27): cvt_S (y<32) + build_wt (y==32) + pack_x0 #1 (y in [33,41)).
// S0t/S1t live in cd's space (exactly 8MB, dead until dense<3>), so pack
// #1's xcat/X0t writes don't race gemm_f8T's S*t reads.
// ---------------------------------------------------------------------------
__global__ __launch_bounds__(256) void prep(const float* __restrict__ Sa,
                                            const float* __restrict__ Sb,
                                            u8* __restrict__ Sha, u8* __restrict__ Shb,
                                            u8* __restrict__ Sta, u8* __restrict__ Stb,
                                            const float* __restrict__ Wru,
                                            const float* __restrict__ Wc,
                                            u16* __restrict__ Wtru,
                                            u16* __restrict__ Wtc,
                                            const float* __restrict__ inputs,
                                            const float* __restrict__ hx,
                                            u8* __restrict__ X0t,
                                            u16* __restrict__ xcat) {
  __shared__ u16 mtile[128 * 76];       // pack tile; cvt_S aliases as u8
  const int t = threadIdx.x;

  if (blockIdx.y == 32) {
    // ---- build_wt for both weight matrices ----
    const int id = blockIdx.z * 32 + blockIdx.x;        // 0..63
    for (int e = id * 256 + t; e < 2 * 128 * KF; e += 64 * 256) {
      int tt = e;
      const float* W = Wru; u16* Wt = Wtru; int ocols = 128;
      if (tt >= 128 * KF) { tt -= 128 * KF; W = Wc; Wt = Wtc; ocols = 64; }
      int o = tt / KF, kf = tt - o * KF;
      float v = 0.0f;
      if (kf < 330 && o < ocols) {
        int m = kf / CC, c = kf - m * CC;
        v = W[(size_t)(c * 5 + m) * ocols + o];
      }
      Wt[tt] = f2bf(v);
    }
    return;
  }

  if (blockIdx.y >= 33) {
    // ---- pack_x0 #1 (useR=0): 512 blocks; writes X0t + xcat m=0 ----
    u16* tile = mtile;
    const int id = ((blockIdx.y - 33) * 2 + blockIdx.z) * 32 + blockIdx.x;
    const int n0 = (id & 15) * 128;
    const int b = id >> 4;
#pragma unroll
    for (int p = 0; p < 8; ++p) {
      const int idx = p * 256 + t;
      const int n = idx >> 4;
      const int u4 = (idx & 15) * 4;
      float4 v = *reinterpret_cast<const float4*>(
          hx + (size_t)b * (NN * 64) + (size_t)(n0 + n) * 64 + u4);
      ushort4 o;
      o.x = f2bf(v.x); o.y = f2bf(v.y); o.z = f2bf(v.z); o.w = f2bf(v.w);
      *reinterpret_cast<ushort4*>(&tile[n * 76 + u4]) = o;
    }
    __syncthreads();
    // X0t fp8 (transposed, k-packed) — paired u16 stores
#pragma unroll
    for (int p = 0; p < 17; ++p) {
      const int idx = p * 256 + t;
      if (idx < 66 * 64) {
        const int c = idx >> 6;
        const int n = (idx & 63) * 2;      // even n; pair (n, n+1)
        float v0, v1;
        if (c < 2) {
          v0 = inputs[(size_t)b * (NN * 2) + (size_t)(n0 + n) * 2 + c];
          v1 = inputs[(size_t)b * (NN * 2) + (size_t)(n0 + n + 1) * 2 + c];
        } else {
          v0 = bf2f(tile[n * 76 + (c - 2)]);
          v1 = bf2f(tile[(n + 1) * 76 + (c - 2)]);
        }
        const int np = (n & ~63) + kperm(n & 63);   // even; kperm(n+1)=np+1
        const u16 w = (u16)f2e4m3(v0) | ((u16)f2e4m3(v1) << 8);
        *reinterpret_cast<u16*>(
            &X0t[(size_t)(b * CC + c) * NN + n0 + np]) = w;
      }
    }
    // xcat m=0 slice (bf16)
#pragma unroll
    for (int p = 0; p < 17; ++p) {
      const int idx = p * 256 + t;
      if (idx < 128 * 33) {
        const int n = idx / 33;
        const int pr = idx - n * 33;
        const int col = pr * 2;
        u16 v0, v1;
        if (col == 0) {
          v0 = f2bf(inputs[(size_t)b * (NN * 2) + (size_t)(n0 + n) * 2 + 0]);
          v1 = f2bf(inputs[(size_t)b * (NN * 2) + (size_t)(n0 + n) * 2 + 1]);
        } else {
          v0 = tile[n * 76 + (col - 2)];
          v1 = tile[n * 76 + (col - 1)];
        }
        ushort2 o2; o2.x = v0; o2.y = v1;
        *reinterpret_cast<ushort2*>(
            xcat + ((size_t)b * NN + n0 + n) * KF + col) = o2;
      }
    }
    return;
  }

  // ---- cvt_S ----
  u8* tile = (u8*)mtile;
  const float* S = blockIdx.z ? Sb : Sa;
  u8* Sh = blockIdx.z ? Shb : Sha;
  u8* St = blockIdx.z ? Stb : Sta;
  const int c0 = blockIdx.x * 64;
  const int r0 = blockIdx.y * 64;
#pragma unroll
  for (int p = 0; p < 4; ++p) {
    const int idx = p * 256 + t;
    const int r = idx >> 4;
    const int c4 = (idx & 15) * 4;     // 0..60, k6 = c4
    float4 v = *reinterpret_cast<const float4*>(S + (size_t)(r0 + r) * NN + c0 + c4);
    union { u8 b[4]; uint32_t w; } o;
    o.b[0] = f2e4m3(v.x * 256.0f); o.b[1] = f2e4m3(v.y * 256.0f);
    o.b[2] = f2e4m3(v.z * 256.0f); o.b[3] = f2e4m3(v.w * 256.0f);
    *reinterpret_cast<uint32_t*>(Sh + (size_t)(r0 + r) * NN + c0 + kperm(c4)) = o.w;
    *reinterpret_cast<uint32_t*>(&tile[r * 68 + c4]) = o.w;
  }
  __syncthreads();
  const int cc = t >> 2;               // 0..63 output row (= global col)
#pragma unroll
  for (int half = 0; half < 2; ++half) {
    const int j = (t & 3) * 2 + half;  // 8B slot 0..7, old p = j*8..j*8+7
    union { u8 b[8]; uint64_t w; } buf;
#pragma unroll
    for (int i = 0; i < 8; ++i) buf.b[i] = tile[(j * 8 + i) * 68 + cc];
    const int npos = 16 * (j & 3) + 8 * (j >> 2);
    *reinterpret_cast<uint64_t*>(St + (size_t)(c0 + cc) * NN + r0 + npos) = buf.w;
  }
}

// ---------------------------------------------------------------------------
// pack_x0 (gconv 2 only, useR=1): X0t[j][n] = concat(inputs, r*hx)
// ALSO writes xcat m=0 slice (bf16, cols 0..65).  Paired u16 X0t stores.
// ---------------------------------------------------------------------------
__global__ __launch_bounds__(256) void pack_x0(const float* __restrict__ inputs,
                                               const float* __restrict__ hx,
                                               const u16* __restrict__ ru,
                                               u8* __restrict__ X0t,
                                               u16* __restrict__ xcat) {
  __shared__ u16 tile[128 * 76];
  const int n0 = blockIdx.x * 128;
  const int b = blockIdx.y;
  const int t = threadIdx.x;
#pragma unroll
  for (int p = 0; p < 8; ++p) {
    const int idx = p * 256 + t;
    const int n = idx >> 4;
    const int u4 = (idx & 15) * 4;
    float4 v = *reinterpret_cast<const float4*>(
        hx + (size_t)b * (NN * 64) + (size_t)(n0 + n) * 64 + u4);
    ushort4 rv = *reinterpret_cast<const ushort4*>(
        ru + ((size_t)b * NN + n0 + n) * 128 + u4);
    v.x *= bf2f(rv.x); v.y *= bf2f(rv.y); v.z *= bf2f(rv.z); v.w *= bf2f(rv.w);
    ushort4 o;
    o.x = f2bf(v.x); o.y = f2bf(v.y); o.z = f2bf(v.z); o.w = f2bf(v.w);
    *reinterpret_cast<ushort4*>(&tile[n * 76 + u4]) = o;
  }
  __syncthreads();
  // X0t fp8 (transposed, k-packed in n) — paired u16 stores (66*64 = 4224)
#pragma unroll
  for (int p = 0; p < 17; ++p) {
    const int idx = p * 256 + t;
    if (idx < 66 * 64) {
      const int c = idx >> 6;
      const int n = (idx & 63) * 2;      // even n; pair (n, n+1)
      float v0, v1;
      if (c < 2) {
        v0 = inputs[(size_t)b * (NN * 2) + (size_t)(n0 + n) * 2 + c];
        v1 = inputs[(size_t)b * (NN * 2) + (size_t)(n0 + n + 1) * 2 + c];
      } else {
        v0 = bf2f(tile[n * 76 + (c - 2)]);
        v1 = bf2f(tile[(n + 1) * 76 + (c - 2)]);
      }
      const int np = (n & ~63) + kperm(n & 63);   // even; kperm(n+1)=np+1
      const u16 w = (u16)f2e4m3(v0) | ((u16)f2e4m3(v1) << 8);
      *reinterpret_cast<u16*>(
          &X0t[(size_t)(b * CC + c) * NN + n0 + np]) = w;
    }
  }
  // xcat m=0 slice (bf16)
#pragma unroll
  for (int p = 0; p < 17; ++p) {
    const int idx = p * 256 + t;
    if (idx < 128 * 33) {
      const int n = idx / 33;
      const int pr = idx - n * 33;
      const int col = pr * 2;
      u16 v0, v1;
      if (col == 0) {
        v0 = f2bf(inputs[(size_t)b * (NN * 2) + (size_t)(n0 + n) * 2 + 0]);
        v1 = f2bf(inputs[(size_t)b * (NN * 2) + (size_t)(n0 + n) * 2 + 1]);
      } else {
        v0 = tile[n * 76 + (col - 2)];
        v1 = tile[n * 76 + (col - 1)];
      }
      ushort2 o2; o2.x = v0; o2.y = v1;
      *reinterpret_cast<ushort2*>(
          xcat + ((size_t)b * NN + n0 + n) * KF + col) = o2;
    }
  }
}

// new_state = u*hx + (1-u)*c   (vectorized — 4 elems/thread)
__global__ __launch_bounds__(256) void final_k(const float* __restrict__ hx,
                                               const u16* __restrict__ ru,
                                               const u16* __restrict__ cd,
                                               float* __restrict__ out) {
  size_t i = (size_t)blockIdx.x * 256 + threadIdx.x;   // 4 elems each
  size_t s = i >> 4;
  int u4 = (int)(i & 15) * 4;
  float4 h = *reinterpret_cast<const float4*>(&hx[s * 64 + u4]);
  ushort4 uu = *reinterpret_cast<const ushort4*>(&ru[s * 128 + 64 + u4]);
  ushort4 cc = *reinterpret_cast<const ushort4*>(&cd[s * 64 + u4]);
  float4 o;
  float ug;
  ug = bf2f(uu.x); o.x = ug * h.x + (1.0f - ug) * bf2f(cc.x);
  ug = bf2f(uu.y); o.y = ug * h.y + (1.0f - ug) * bf2f(cc.y);
  ug = bf2f(uu.z); o.z = ug * h.z + (1.0f - ug) * bf2f(cc.z);
  ug = bf2f(uu.w); o.w = ug * h.w + (1.0f - ug) * bf2f(cc.w);
  *reinterpret_cast<float4*>(&out[s * 64 + u4]) = o;
}

extern "C" void kernel_launch(void* const* d_in, const int* in_sizes, int n_in,
                              void* d_out, int out_size, void* d_ws, size_t ws_size,
                              hipStream_t stream) {
  const float* inputs = (const float*)d_in[0];
  const float* hx     = (const float*)d_in[1];
  const float* S0     = (const float*)d_in[2];
  const float* S1     = (const float*)d_in[3];
  const float* Wru    = (const float*)d_in[4];
  const float* bru    = (const float*)d_in[5];
  const float* Wc     = (const float*)d_in[6];
  const float* bc     = (const float*)d_in[7];
  float* out = (float*)d_out;

  // workspace layout (~84 MB)
  u8* ws8 = (u8*)d_ws;
  u8* S0h = ws8;                                   // [2048][2048] fp8 (x2^8, k-packed)
  u8* S1h = S0h + (size_t)NN * NN;
  u8* X0t = S1h + (size_t)NN * NN;                 // [JR][2048] fp8 k-packed
  u16* xcat = (u16*)(X0t + (size_t)JR * NN);       // [65536][352] bf16
  u16* Wtru = xcat + (size_t)SROWS * KF;           // [128][352]
  u16* Wtc  = Wtru + (size_t)128 * KF;
  u16* ru   = Wtc + (size_t)128 * KF;              // [65536][128]
  u16* cd   = ru + (size_t)SROWS * 128;            // [65536][64]
  // transient aliases:
  // S0t/S1t live in cd's space (exactly 8MB; cd is dead until dense<3>).
  u8* S0t = (u8*)cd;                               // S^T fp8 k-packed
  u8* S1t = S0t + (size_t)NN * NN;
  u8* T0 = (u8*)d_out;                             // 2S^2-I fp8 (x2^8, k-packed) in d_out
  u8* T1 = T0 + (size_t)NN * NN;                   // (8MB of 16.78; final_k rewrites)

  dim3 b256(256);
  dim3 b512(512);
  // merged cvt_S (y<32) + build_wt (y==32) + pack_x0 #1 (y in [33,41))
  prep<<<dim3(NN / 64, NN / 64 + 9, 2), b256, 0, stream>>>(
      S0, S1, S0h, S1h, S0t, S1t, Wru, Wc, Wtru, Wtc,
      inputs, hx, X0t, xcat);

  // T = 2*S*S - I (fp8 out, x2^8, k-packed): 128x128 tiles, 16x16x2 = 512 blocks
  gemm_f8T<<<dim3(NN / 128, NN / 128, 2), b512, 0, stream>>>(
      S0h, S1h, S0t, S1t, T0, T1, NN, NN, NN, NN);

  // 16 x 8 x 4 = 512 blocks; leftover 64 j-rows folded into mb<4 slivers.
  const dim3 gdiff(16, NN / 256, 4);
  const dim3 gdense(SROWS / 128);            // 512 blocks
  const dim3 gpx0(NN / 128, BB);

  // ---- gconv 1 ----  (pack #1 already done inside prep)
  gemm_f8<5><<<gdiff, b512, 0, stream>>>(
      X0t, X0t, X0t, X0t,  S0h, T0, S1h, T1,
      (void*)xcat, (void*)xcat, (void*)xcat, (void*)xcat,
      NN, NN, NN, KF, JREAL);
  gemm_dense<2><<<gdense, b256, 0, stream>>>(xcat, Wtru, ru, bru, KF, KF, KF, 128, 128);

  // ---- gconv 2 ----
  pack_x0<<<gpx0, b256, 0, stream>>>(inputs, hx, ru, X0t, xcat);
  gemm_f8<5><<<gdiff, b512, 0, stream>>>(
      X0t, X0t, X0t, X0t,  S0h, T0, S1h, T1,
      (void*)xcat, (void*)xcat, (void*)xcat, (void*)xcat,
      NN, NN, NN, KF, JREAL);
  // dense<3> writes cd (overwrites the long-dead S0t/S1t)
  gemm_dense<3><<<gdense, b256, 0, stream>>>(xcat, Wtc, cd, bc, KF, KF, KF, 64, 64);

  // ---- combine (vectorized) ----
  final_k<<<dim3(SROWS * 64 / 1024), b256, 0, stream>>>(hx, ru, cd, out);
}

// Round 15
// 228.900 us; speedup vs baseline: 1.0064x; 1.0064x over previous
//
#include <hip/hip_runtime.h>
#include <hip/hip_bf16.h>
#include <cstdint>
#include <cstddef>

typedef unsigned short u16;
typedef unsigned char u8;
using f32x4 = __attribute__((ext_vector_type(4))) float;
using s16x8 = __attribute__((ext_vector_type(8))) short;
using s64x2 = __attribute__((ext_vector_type(2))) long;

#define NN 2048      // nodes
#define BB 32        // batch
#define CC 66        // input_size (2 + 64)
#define JREAL 2112   // BB*CC real j-rows
#define JR 2176      // padded
#define KF 352       // 5*66 = 330 padded to 11*32
#define SROWS 65536  // BB*NN

// k-paired packed layout within each 64-byte K-block:
//   new[16*q + 8*h + b] = old[8*q + 32*h + b],  q:0..3, h:0..1, b:0..7
// NOTE: even/odd k-pairs stay ADJACENT under kperm (b=k&7 increments within
// an octet), enabling paired 2-byte stores of fp8 pairs.
__device__ __forceinline__ int kperm(int k6) {
  return 16 * ((k6 >> 3) & 3) + 8 * (k6 >> 5) + (k6 & 7);
}

__device__ __forceinline__ float bf2f(u16 u) {
  union { uint32_t i; float f; } v; v.i = ((uint32_t)u) << 16; return v.f;
}
__device__ __forceinline__ u16 f2bf(float f) {
  union { float f; uint32_t i; } v; v.f = f;
  uint32_t x = v.i;
  x += 0x7fffu + ((x >> 16) & 1u);   // RNE
  return (u16)(x >> 16);
}
// f32 -> OCP e4m3fn, RNE, saturate to 448.
__device__ __forceinline__ u8 f2e4m3(float x) {
  union { float f; uint32_t i; } v; v.f = x;
  uint32_t s = (v.i >> 24) & 0x80u;
  float a = fabsf(x);
  if (a >= 464.0f) return (u8)(s | 0x7Eu);
  if (a < 0.015625f) {
    int q = (int)rintf(a * 512.0f);
    return (u8)(s | (uint32_t)q);
  }
  union { float f; uint32_t i; } u; u.f = a;
  uint32_t lsb = (u.i >> 20) & 1u;
  u.i += 0x0007FFFFu + lsb;
  int e = (int)(u.i >> 23) - 127;
  uint32_t m = (u.i >> 20) & 7u;
  return (u8)(s | ((uint32_t)(e + 7) << 3) | m);
}

__device__ __forceinline__ void async_cp16(const u8* g, u8* l) {
  __builtin_amdgcn_global_load_lds(
      (const __attribute__((address_space(1))) unsigned int*)g,
      (__attribute__((address_space(3))) unsigned int*)l, 16, 0, 0);
}
__device__ __forceinline__ void async_cp16u(const u16* g, u16* l) {
  __builtin_amdgcn_global_load_lds(
      (const __attribute__((address_space(1))) unsigned int*)g,
      (__attribute__((address_space(3))) unsigned int*)l, 16, 0, 0);
}

// ---------------------------------------------------------------------------
// gemm_f8 (r16 K-loop — measured 65.7us, MfmaUtil 52, FETCH 32MB):
// C tile 128(M=j) x 256(N=n) = A * B^T, fp8 e4m3, k-paired layout, BK=64,
// 8 waves 64x64, conflict-free single-b128 fragment reads.  3-slot ring
// (76.8 KB, 2 blocks/CU), prefetch 2, 4 phases/K-tile each {ds_read || 1
// gload -> barrier -> lgkmcnt(0) -> setprio(1) -> 8(+2 sliver) MFMA ->
// setprio(0) -> barrier}; counted vmcnt(3)/(4) once per K-tile at phase 3.
// (r17 2x16-merge and r18 256^2 both regressed — this is the local optimum.)
// Sliver: leftover 64 j-rows folded into mb<4 blocks.
// EPI 5 (r23/r24, bank-conflict-free measured 0): single-pass scatter, tl
// stride 132 u16 so 4 contiguous j-slots per (mi,ni) store as ONE ushort4;
// sliver scatter paired to u32.
// ---------------------------------------------------------------------------
template <int EPI>
__global__ __launch_bounds__(512, 2) void gemm_f8(
    const u8* __restrict__ A0, const u8* __restrict__ A1,
    const u8* __restrict__ A2, const u8* __restrict__ A3,
    const u8* __restrict__ B0, const u8* __restrict__ B1,
    const u8* __restrict__ B2, const u8* __restrict__ B3,
    void* __restrict__ C0, void* __restrict__ C1,
    void* __restrict__ C2, void* __restrict__ C3,
    int K, int lda, int ldb, int ldout, int mlimit)
{
  // slot: A 128x64B (8KB) + B 256x64B (16KB) + A-sliver 16x64B (1KB) = 25600
  __shared__ u8 lds[3 * 25600];

  const int gx = gridDim.x, gy = gridDim.y;
  const int nwg = gx * gy * gridDim.z;
  const int orig = blockIdx.x + gx * (blockIdx.y + gy * blockIdx.z);
  const int cpx = nwg >> 3;
  const int swz = (orig & 7) * cpx + (orig >> 3);
  const int mb = swz % gx;
  const int t1 = swz / gx;
  const int nb = t1 % gy;
  const int zb = t1 / gy;

  const u8* A = (zb == 0) ? A0 : (zb == 1) ? A1 : (zb == 2) ? A2 : A3;
  const u8* B = (zb == 0) ? B0 : (zb == 1) ? B1 : (zb == 2) ? B2 : B3;
  void* Cv    = (zb == 0) ? C0 : (zb == 1) ? C1 : (zb == 2) ? C2 : C3;

  const int tid = threadIdx.x;
  const int wid = tid >> 6;
  const int lane = tid & 63;
  const int m0 = mb * 128;
  const int n0 = nb * 256;
  const int wm = (wid >> 2) * 64;   // 2 wave-rows
  const int wn = (wid & 3) * 64;    // 4 wave-cols

  // sliver of leftover rows j in [2048,2112): blocks mb<4 take 16 rows each
  const bool xtra = (EPI == 5) && (mb < 4);
  const int xrow0 = 2048 + mb * 16;
  const bool xw = xtra && (wid == 0);   // staging wave for the sliver
  const bool xm = xtra && (wid < 4);    // compute waves (wm==0)

  // ---- staging: 16B/lane; source granule pre-swizzled (LDS dest linear) ----
  const int srow = wid * 16 + (lane >> 2);                  // 0..127 per pass
  const int sk   = ((lane & 3) ^ ((lane >> 3) & 3)) * 16;   // swizzled granule
  const u8* gA = A + (size_t)(m0 + srow) * lda + sk;
  const u8* gB = B + (size_t)(n0 + srow) * ldb + sk;        // +128*ldb pass 1
  const u8* gAx = A + (size_t)(xrow0 + (lane >> 2)) * lda + sk;  // 16 rows
  u8* ldsA  = &lds[wid * 1024];           // + slot*25600
  u8* ldsB0 = &lds[8192 + wid * 1024];
  u8* ldsB1 = &lds[16384 + wid * 1024];
  u8* ldsAx = &lds[24576];                // 1KB sliver region (wave 0 writes)

  // ---- ds_read: one b128 per fragment-pair, granule (hi ^ rq) ----
  const int r16 = lane & 15;
  const int hi = lane >> 4;
  const int rq = (r16 >> 1) & 3;
  const int goff = (hi ^ rq) * 16;
  const int abase = (wm + r16) * 64 + goff;           // + mi*1024
  const int bbase = 8192 + (wn + r16) * 64 + goff;    // + ni*1024
  const int xbase = 24576 + r16 * 64 + goff;          // sliver fragment

  f32x4 acc[4][4] = {};
  f32x4 accx[4] = {};
  const int nt = K >> 6;   // K-tiles of 64

#define STAGE_ALL(T_, SO_) { const int k0_ = (T_) * 64;                      \
    async_cp16(gA + k0_, ldsA + (SO_));                                      \
    async_cp16(gB + k0_, ldsB0 + (SO_));                                     \
    async_cp16(gB + (size_t)128 * ldb + k0_, ldsB1 + (SO_));                 \
    if (xw) async_cp16(gAx + k0_, ldsAx + (SO_)); }

  STAGE_ALL(0, 0);
  STAGE_ALL(1, 25600);
  // tile 0 landed (wave-local count: wave 0 of sliver blocks has 4/stage)
  if (xw) { asm volatile("s_waitcnt vmcnt(4)" ::: "memory"); }
  else    { asm volatile("s_waitcnt vmcnt(3)" ::: "memory"); }
  __builtin_amdgcn_s_barrier();

  int scur = 0;                 // slot of tile t
  for (int t = 0; t < nt; ++t) {
    const int soff = scur * 25600;
    const bool more = (t + 2) < nt;
    int sst = scur + 2; if (sst >= 3) sst -= 3;
    const int so2 = sst * 25600;
    const int k2 = (t + 2) * 64;

    s64x2 af[4], bq, axf;

    // ---- phase 0: af[0..3] + bq(n=0) (+ sliver axf) || stage A(t+2) ----
#pragma unroll
    for (int mi = 0; mi < 4; ++mi)
      af[mi] = *(const s64x2*)&lds[soff + abase + mi * 1024];
    bq = *(const s64x2*)&lds[soff + bbase];
    if (xm) axf = *(const s64x2*)&lds[soff + xbase];
    if (more) async_cp16(gA + k2, ldsA + so2);
    __builtin_amdgcn_s_barrier();
    asm volatile("s_waitcnt lgkmcnt(0)" ::: "memory");
    __builtin_amdgcn_s_setprio(1);
#pragma unroll
    for (int h = 0; h < 2; ++h) {
#pragma unroll
      for (int mi = 0; mi < 4; ++mi)
        acc[mi][0] = __builtin_amdgcn_mfma_f32_16x16x32_fp8_fp8(
            af[mi][h], bq[h], acc[mi][0], 0, 0, 0);
      if (xm) accx[0] = __builtin_amdgcn_mfma_f32_16x16x32_fp8_fp8(
            axf[h], bq[h], accx[0], 0, 0, 0);
    }
    __builtin_amdgcn_s_setprio(0);
    __builtin_amdgcn_s_barrier();

    // ---- phase 1: bq(n=1) || stage B0(t+2) ----
    bq = *(const s64x2*)&lds[soff + bbase + 1024];
    if (more) async_cp16(gB + k2, ldsB0 + so2);
    __builtin_amdgcn_s_barrier();
    asm volatile("s_waitcnt lgkmcnt(0)" ::: "memory");
    __builtin_amdgcn_s_setprio(1);
#pragma unroll
    for (int h = 0; h < 2; ++h) {
#pragma unroll
      for (int mi = 0; mi < 4; ++mi)
        acc[mi][1] = __builtin_amdgcn_mfma_f32_16x16x32_fp8_fp8(
            af[mi][h], bq[h], acc[mi][1], 0, 0, 0);
      if (xm) accx[1] = __builtin_amdgcn_mfma_f32_16x16x32_fp8_fp8(
            axf[h], bq[h], accx[1], 0, 0, 0);
    }
    __builtin_amdgcn_s_setprio(0);
    __builtin_amdgcn_s_barrier();

    // ---- phase 2: bq(n=2) || stage B1(t+2) ----
    bq = *(const s64x2*)&lds[soff + bbase + 2048];
    if (more) async_cp16(gB + (size_t)128 * ldb + k2, ldsB1 + so2);
    __builtin_amdgcn_s_barrier();
    asm volatile("s_waitcnt lgkmcnt(0)" ::: "memory");
    __builtin_amdgcn_s_setprio(1);
#pragma unroll
    for (int h = 0; h < 2; ++h) {
#pragma unroll
      for (int mi = 0; mi < 4; ++mi)
        acc[mi][2] = __builtin_amdgcn_mfma_f32_16x16x32_fp8_fp8(
            af[mi][h], bq[h], acc[mi][2], 0, 0, 0);
      if (xm) accx[2] = __builtin_amdgcn_mfma_f32_16x16x32_fp8_fp8(
            axf[h], bq[h], accx[2], 0, 0, 0);
    }
    __builtin_amdgcn_s_setprio(0);
    __builtin_amdgcn_s_barrier();

    // ---- phase 3: bq(n=3) || stage sliver(t+2); counted vmcnt ----
    bq = *(const s64x2*)&lds[soff + bbase + 3072];
    if (more && xw) async_cp16(gAx + k2, ldsAx + so2);
    __builtin_amdgcn_s_barrier();
    asm volatile("s_waitcnt lgkmcnt(0)" ::: "memory");
    __builtin_amdgcn_s_setprio(1);
#pragma unroll
    for (int h = 0; h < 2; ++h) {
#pragma unroll
      for (int mi = 0; mi < 4; ++mi)
        acc[mi][3] = __builtin_amdgcn_mfma_f32_16x16x32_fp8_fp8(
            af[mi][h], bq[h], acc[mi][3], 0, 0, 0);
      if (xm) accx[3] = __builtin_amdgcn_mfma_f32_16x16x32_fp8_fp8(
            axf[h], bq[h], accx[3], 0, 0, 0);
    }
    __builtin_amdgcn_s_setprio(0);
    if (more) {
      if (xw) { asm volatile("s_waitcnt vmcnt(4)" ::: "memory"); }
      else    { asm volatile("s_waitcnt vmcnt(3)" ::: "memory"); }
    } else {
      asm volatile("s_waitcnt vmcnt(0)" ::: "memory");
    }
    __builtin_amdgcn_s_barrier();
    scur = (scur + 1 == 3) ? 0 : scur + 1;
  }
#undef STAGE_ALL

  const int lr = (lane >> 4) * 4;
  const int lc = lane & 15;

  if (EPI == 5) {
    // fused xcat scatter: acc[j][n] -> xcat[(b*NN+n)][ (zb+1)*66 + c ]
    // single-pass: tl = 256 np x 128 j, stride 132 u16 (67.6 KB <= 76.8 KB;
    // 264B row pitch is 8B-aligned -> ushort4 stores)
    u16* tl = (u16*)lds;
    u16* xc = (u16*)Cv;
    // sliver epilogue: direct scatter, j in [xrow0,xrow0+16) => b=31,
    // c=j-2046; paired u32 stores (all index terms even, 4B-aligned).
    if (xm) {
#pragma unroll
      for (int ni = 0; ni < 4; ++ni) {
        const int ng = n0 + wn + ni * 16 + lc;
        const size_t base = ((size_t)31 * NN + ng) * KF +
                            (size_t)(zb + 1) * CC + (xrow0 + lr - 2046);
        const uint32_t w0 = (uint32_t)f2bf(accx[ni][0] * 0.00390625f) |
                            ((uint32_t)f2bf(accx[ni][1] * 0.00390625f) << 16);
        const uint32_t w1 = (uint32_t)f2bf(accx[ni][2] * 0.00390625f) |
                            ((uint32_t)f2bf(accx[ni][3] * 0.00390625f) << 16);
        *reinterpret_cast<uint32_t*>(&xc[base])     = w0;
        *reinterpret_cast<uint32_t*>(&xc[base + 2]) = w1;
      }
    }
    // all waves write their full acc once (K-loop's final barrier already
    // guarantees ring-LDS reads are done); 4 contiguous j per ushort4
#pragma unroll
    for (int mi = 0; mi < 4; ++mi)
#pragma unroll
      for (int ni = 0; ni < 4; ++ni) {
        const int np = wn + ni * 16 + lc;        // 0..255
        const int j = wm + mi * 16 + lr;         // multiple of 4
        ushort4 w4;
        w4.x = f2bf(acc[mi][ni][0] * 0.00390625f);
        w4.y = f2bf(acc[mi][ni][1] * 0.00390625f);
        w4.z = f2bf(acc[mi][ni][2] * 0.00390625f);
        w4.w = f2bf(acc[mi][ni][3] * 0.00390625f);
        *reinterpret_cast<ushort4*>(&tl[np * 132 + j]) = w4;
      }
    __syncthreads();
    // write out: paired u32 stores — thread handles j-pair (2k, 2k+1);
    // pairs never straddle a 66-boundary (66 even), all indices u32-aligned.
    for (int p = 0; p < 32; ++p) {
      const int idx = p * 512 + tid;      // 0..16383
      const int jj = (idx & 63) * 2;      // 64 j-pairs
      const int np = idx >> 6;            // 0..255
      const int j = m0 + jj;              // < 2048 (sliver covers the rest)
      const int b = j / CC;
      const int c = j - b * CC;
      const int ng = n0 + np;
      *reinterpret_cast<uint32_t*>(
          &xc[((size_t)b * NN + ng) * KF + (size_t)(zb + 1) * CC + c]) =
          *reinterpret_cast<const uint32_t*>(&tl[np * 132 + jj]);
    }
  } else {
#pragma unroll
    for (int mi = 0; mi < 4; ++mi)
#pragma unroll
      for (int ni = 0; ni < 4; ++ni) {
        const int colg = n0 + wn + ni * 16 + lc;
#pragma unroll
        for (int r = 0; r < 4; ++r) {
          const int rowg = m0 + wm + mi * 16 + lr + r;
          if (rowg < mlimit) {
            if (EPI == 0) {
              ((u16*)Cv)[(size_t)rowg * ldout + colg] =
                  f2bf(acc[mi][ni][r] * 0.00390625f);          // * 2^-8
            } else {
              float v = acc[mi][ni][r] * 0.0078125f -          // * 2^-7
                        ((rowg == colg) ? 256.0f : 0.0f);
              const int cpk = (colg & ~63) + kperm(colg & 63);
              ((u8*)Cv)[(size_t)rowg * ldout + cpk] = f2e4m3(v);
            }
          }
        }
      }
  }
}

// ---------------------------------------------------------------------------
// gemm_f8T (r16/r27 form — r28's 2-phase port measured neutral, reverted):
// T = 2*S*S - I, tile 128 x 128 -> grid 16x16x2 = 512 blocks (2/CU).
// 8 waves, wave-tile 64x32 (acc[4][2]), BK=64, 3-slot ring 48 KB, counted
// vmcnt(2), single MFMA cluster per K-tile.
// Out: fp8 = acc*2^-7 - 256*I at k-permuted col (x2^8 scale kept).
// S0t/S1t live in cd's space (NOT xcat) — pack #1 can't race this kernel.
// ---------------------------------------------------------------------------
__global__ __launch_bounds__(512, 2) void gemm_f8T(
    const u8* __restrict__ A0, const u8* __restrict__ A1,
    const u8* __restrict__ B0, const u8* __restrict__ B1,
    u8* __restrict__ C0, u8* __restrict__ C1,
    int K, int lda, int ldb, int ldout)
{
  __shared__ u8 lds[3 * 16384];   // slot: A 128x64B (8KB) + B 128x64B (8KB)

  const int gx = gridDim.x, gy = gridDim.y;
  const int nwg = gx * gy * gridDim.z;
  const int orig = blockIdx.x + gx * (blockIdx.y + gy * blockIdx.z);
  const int cpx = nwg >> 3;
  const int swz = (orig & 7) * cpx + (orig >> 3);
  const int mb = swz % gx;
  const int t1 = swz / gx;
  const int nb = t1 % gy;
  const int zb = t1 / gy;

  const u8* A = zb ? A1 : A0;
  const u8* B = zb ? B1 : B0;
  u8* C = zb ? C1 : C0;

  const int tid = threadIdx.x;
  const int wid = tid >> 6;
  const int lane = tid & 63;
  const int m0 = mb * 128;
  const int n0 = nb * 128;
  const int wm = (wid >> 2) * 64;   // 2 wave-rows (64)
  const int wn = (wid & 3) * 32;    // 4 wave-cols (32)

  const int srow = wid * 16 + (lane >> 2);                  // 0..127
  const int sk   = ((lane & 3) ^ ((lane >> 3) & 3)) * 16;   // swizzled granule
  const u8* gA = A + (size_t)(m0 + srow) * lda + sk;
  const u8* gB = B + (size_t)(n0 + srow) * ldb + sk;
  u8* ldsA = &lds[wid * 1024];            // + slot*16384
  u8* ldsB = &lds[8192 + wid * 1024];

  const int r16 = lane & 15;
  const int hi = lane >> 4;
  const int rq = (r16 >> 1) & 3;
  const int goff = (hi ^ rq) * 16;
  const int abase = (wm + r16) * 64 + goff;           // + mi*1024, mi 0..3
  const int bbase = 8192 + (wn + r16) * 64 + goff;    // + ni*1024, ni 0..1

  f32x4 acc[4][2] = {};
  const int nt = K >> 6;

#define STAGE(T_, SO_) { const int k0_ = (T_) * 64;                          \
    async_cp16(gA + k0_, ldsA + (SO_));                                      \
    async_cp16(gB + k0_, ldsB + (SO_)); }

  STAGE(0, 0);
  STAGE(1, 16384);
  asm volatile("s_waitcnt vmcnt(2)" ::: "memory");   // tile 0 landed
  __builtin_amdgcn_s_barrier();

  int scur = 0;
  for (int t = 0; t < nt; ++t) {
    const int soff = scur * 16384;
    const bool more = (t + 2) < nt;
    if (more) {
      int sst = scur + 2; if (sst >= 3) sst -= 3;
      STAGE(t + 2, sst * 16384);
    }
    s64x2 af[4], bfr[2];
#pragma unroll
    for (int mi = 0; mi < 4; ++mi)
      af[mi] = *(const s64x2*)&lds[soff + abase + mi * 1024];
#pragma unroll
    for (int ni = 0; ni < 2; ++ni)
      bfr[ni] = *(const s64x2*)&lds[soff + bbase + ni * 1024];
    __builtin_amdgcn_s_setprio(1);
#pragma unroll
    for (int h = 0; h < 2; ++h)
#pragma unroll
      for (int mi = 0; mi < 4; ++mi)
#pragma unroll
        for (int ni = 0; ni < 2; ++ni)
          acc[mi][ni] = __builtin_amdgcn_mfma_f32_16x16x32_fp8_fp8(
              af[mi][h], bfr[ni][h], acc[mi][ni], 0, 0, 0);
    __builtin_amdgcn_s_setprio(0);
    if (more) { asm volatile("s_waitcnt vmcnt(2)" ::: "memory"); }
    else      { asm volatile("s_waitcnt vmcnt(0)" ::: "memory"); }
    __builtin_amdgcn_s_barrier();
    scur = (scur + 1 == 3) ? 0 : scur + 1;
  }
#undef STAGE

  const int lr = (lane >> 4) * 4;
  const int lc = lane & 15;
#pragma unroll
  for (int mi = 0; mi < 4; ++mi)
#pragma unroll
    for (int ni = 0; ni < 2; ++ni) {
      const int colg = n0 + wn + ni * 16 + lc;
      const int cpk = (colg & ~63) + kperm(colg & 63);
#pragma unroll
      for (int r = 0; r < 4; ++r) {
        const int rowg = m0 + wm + mi * 16 + lr + r;
        float v = acc[mi][ni][r] * 0.0078125f -
                  ((rowg == colg) ? 256.0f : 0.0f);
        C[(size_t)rowg * ldout + cpk] = f2e4m3(v);
      }
    }
}

// ---------------------------------------------------------------------------
// gemm_dense (r16-exact): 128x128 2-barrier bf16 kernel for the dense layers
// (N=128, K=352).  EPI 2: sigmoid(acc+bias); EPI 3: tanh(acc+bias).
// Dedicated streaming kernels (pack_x0/final_k) measured FASTER than fusing
// this epilogue (r19/r20: +9us net; r25 isolated final_k fusion: +6us).
// ---------------------------------------------------------------------------
template <int EPI>
__global__ __launch_bounds__(256) void gemm_dense(
    const u16* __restrict__ A, const u16* __restrict__ B, u16* __restrict__ C,
    const float* __restrict__ bias,
    int K, int lda, int ldb, int ldout, int nstore)
{
  __shared__ u16 At[128 * 32];
  __shared__ u16 Bt[128 * 32];
  const int nwg = gridDim.x;
  const int orig = blockIdx.x;
  const int cpx = nwg >> 3;
  const int swz = (orig & 7) * cpx + (orig >> 3);
  const int mb = swz;

  const int tid = threadIdx.x;
  const int wid = tid >> 6;
  const int lane = tid & 63;
  const int m0 = mb * 128;
  const int wm = (wid >> 1) * 64;
  const int wn = (wid & 1) * 64;
  const int rA = lane >> 2;
  const int kA = ((lane & 3) ^ ((lane >> 3) & 3)) * 8;

  f32x4 acc[4][4] = {};

  const int c0 = wid * 2, c1 = wid * 2 + 1;
  const u16* gA0 = A + (size_t)(m0 + c0 * 16 + rA) * lda + kA;
  const u16* gA1 = A + (size_t)(m0 + c1 * 16 + rA) * lda + kA;
  const u16* gB0 = B + (size_t)(c0 * 16 + rA) * ldb + kA;
  const u16* gB1 = B + (size_t)(c1 * 16 + rA) * ldb + kA;

  for (int k0 = 0; k0 < K; k0 += 32) {
    async_cp16u(gA0 + k0, &At[c0 * 512]);
    async_cp16u(gA1 + k0, &At[c1 * 512]);
    async_cp16u(gB0 + k0, &Bt[c0 * 512]);
    async_cp16u(gB1 + k0, &Bt[c1 * 512]);
    __syncthreads();
    s16x8 af[4], bfr[4];
    const int r16 = lane & 15;
    const int cswz = ((lane >> 4) ^ ((r16 >> 1) & 3)) << 3;
#pragma unroll
    for (int mi = 0; mi < 4; ++mi)
      af[mi] = *(const s16x8*)&At[(wm + mi * 16 + r16) * 32 + cswz];
#pragma unroll
    for (int ni = 0; ni < 4; ++ni)
      bfr[ni] = *(const s16x8*)&Bt[(wn + ni * 16 + r16) * 32 + cswz];
#pragma unroll
    for (int mi = 0; mi < 4; ++mi)
#pragma unroll
      for (int ni = 0; ni < 4; ++ni)
        acc[mi][ni] = __builtin_amdgcn_mfma_f32_16x16x32_bf16(af[mi], bfr[ni], acc[mi][ni], 0, 0, 0);
    __syncthreads();
  }

  const int lr = (lane >> 4) * 4;
  const int lc = lane & 15;
#pragma unroll
  for (int mi = 0; mi < 4; ++mi) {
#pragma unroll
    for (int ni = 0; ni < 4; ++ni) {
      const int colg = wn + ni * 16 + lc;
#pragma unroll
      for (int r = 0; r < 4; ++r) {
        const int rowg = m0 + wm + mi * 16 + lr + r;
        float v = acc[mi][ni][r];
        if (EPI == 2) { v += bias[colg]; v = 1.0f / (1.0f + __expf(-v)); }
        if (EPI == 3) { v += bias[colg]; v = tanhf(v); }
        if (colg < nstore)
          C[(size_t)rowg * ldout + colg] = f2bf(v);
      }
    }
  }
}

// ---------------------------------------------------------------------------
// prep (r27): cvt_S (y<32) + build_wt (y==32) + pack_x0 #1 (y in [33,41)).
// S0t/S1t live in cd's space (exactly 8MB, dead until dense<3>), so pack
// #1's xcat/X0t writes don't race gemm_f8T's S*t reads.
// ---------------------------------------------------------------------------
__global__ __launch_bounds__(256) void prep(const float* __restrict__ Sa,
                                            const float* __restrict__ Sb,
                                            u8* __restrict__ Sha, u8* __restrict__ Shb,
                                            u8* __restrict__ Sta, u8* __restrict__ Stb,
                                            const float* __restrict__ Wru,
                                            const float* __restrict__ Wc,
                                            u16* __restrict__ Wtru,
                                            u16* __restrict__ Wtc,
                                            const float* __restrict__ inputs,
                                            const float* __restrict__ hx,
                                            u8* __restrict__ X0t,
                                            u16* __restrict__ xcat) {
  __shared__ u16 mtile[128 * 76];       // pack tile; cvt_S aliases as u8
  const int t = threadIdx.x;

  if (blockIdx.y == 32) {
    // ---- build_wt for both weight matrices ----
    const int id = blockIdx.z * 32 + blockIdx.x;        // 0..63
    for (int e = id * 256 + t; e < 2 * 128 * KF; e += 64 * 256) {
      int tt = e;
      const float* W = Wru; u16* Wt = Wtru; int ocols = 128;
      if (tt >= 128 * KF) { tt -= 128 * KF; W = Wc; Wt = Wtc; ocols = 64; }
      int o = tt / KF, kf = tt - o * KF;
      float v = 0.0f;
      if (kf < 330 && o < ocols) {
        int m = kf / CC, c = kf - m * CC;
        v = W[(size_t)(c * 5 + m) * ocols + o];
      }
      Wt[tt] = f2bf(v);
    }
    return;
  }

  if (blockIdx.y >= 33) {
    // ---- pack_x0 #1 (useR=0): 512 blocks; writes X0t + xcat m=0 ----
    u16* tile = mtile;
    const int id = ((blockIdx.y - 33) * 2 + blockIdx.z) * 32 + blockIdx.x;
    const int n0 = (id & 15) * 128;
    const int b = id >> 4;
#pragma unroll
    for (int p = 0; p < 8; ++p) {
      const int idx = p * 256 + t;
      const int n = idx >> 4;
      const int u4 = (idx & 15) * 4;
      float4 v = *reinterpret_cast<const float4*>(
          hx + (size_t)b * (NN * 64) + (size_t)(n0 + n) * 64 + u4);
      ushort4 o;
      o.x = f2bf(v.x); o.y = f2bf(v.y); o.z = f2bf(v.z); o.w = f2bf(v.w);
      *reinterpret_cast<ushort4*>(&tile[n * 76 + u4]) = o;
    }
    __syncthreads();
    // X0t fp8 (transposed, k-packed) — paired u16 stores
#pragma unroll
    for (int p = 0; p < 17; ++p) {
      const int idx = p * 256 + t;
      if (idx < 66 * 64) {
        const int c = idx >> 6;
        const int n = (idx & 63) * 2;      // even n; pair (n, n+1)
        float v0, v1;
        if (c < 2) {
          v0 = inputs[(size_t)b * (NN * 2) + (size_t)(n0 + n) * 2 + c];
          v1 = inputs[(size_t)b * (NN * 2) + (size_t)(n0 + n + 1) * 2 + c];
        } else {
          v0 = bf2f(tile[n * 76 + (c - 2)]);
          v1 = bf2f(tile[(n + 1) * 76 + (c - 2)]);
        }
        const int np = (n & ~63) + kperm(n & 63);   // even; kperm(n+1)=np+1
        const u16 w = (u16)f2e4m3(v0) | ((u16)f2e4m3(v1) << 8);
        *reinterpret_cast<u16*>(
            &X0t[(size_t)(b * CC + c) * NN + n0 + np]) = w;
      }
    }
    // xcat m=0 slice (bf16)
#pragma unroll
    for (int p = 0; p < 17; ++p) {
      const int idx = p * 256 + t;
      if (idx < 128 * 33) {
        const int n = idx / 33;
        const int pr = idx - n * 33;
        const int col = pr * 2;
        u16 v0, v1;
        if (col == 0) {
          v0 = f2bf(inputs[(size_t)b * (NN * 2) + (size_t)(n0 + n) * 2 + 0]);
          v1 = f2bf(inputs[(size_t)b * (NN * 2) + (size_t)(n0 + n) * 2 + 1]);
        } else {
          v0 = tile[n * 76 + (col - 2)];
          v1 = tile[n * 76 + (col - 1)];
        }
        ushort2 o2; o2.x = v0; o2.y = v1;
        *reinterpret_cast<ushort2*>(
            xcat + ((size_t)b * NN + n0 + n) * KF + col) = o2;
      }
    }
    return;
  }

  // ---- cvt_S ----
  u8* tile = (u8*)mtile;
  const float* S = blockIdx.z ? Sb : Sa;
  u8* Sh = blockIdx.z ? Shb : Sha;
  u8* St = blockIdx.z ? Stb : Sta;
  const int c0 = blockIdx.x * 64;
  const int r0 = blockIdx.y * 64;
#pragma unroll
  for (int p = 0; p < 4; ++p) {
    const int idx = p * 256 + t;
    const int r = idx >> 4;
    const int c4 = (idx & 15) * 4;     // 0..60, k6 = c4
    float4 v = *reinterpret_cast<const float4*>(S + (size_t)(r0 + r) * NN + c0 + c4);
    union { u8 b[4]; uint32_t w; } o;
    o.b[0] = f2e4m3(v.x * 256.0f); o.b[1] = f2e4m3(v.y * 256.0f);
    o.b[2] = f2e4m3(v.z * 256.0f); o.b[3] = f2e4m3(v.w * 256.0f);
    *reinterpret_cast<uint32_t*>(Sh + (size_t)(r0 + r) * NN + c0 + kperm(c4)) = o.w;
    *reinterpret_cast<uint32_t*>(&tile[r * 68 + c4]) = o.w;
  }
  __syncthreads();
  const int cc = t >> 2;               // 0..63 output row (= global col)
#pragma unroll
  for (int half = 0; half < 2; ++half) {
    const int j = (t & 3) * 2 + half;  // 8B slot 0..7, old p = j*8..j*8+7
    union { u8 b[8]; uint64_t w; } buf;
#pragma unroll
    for (int i = 0; i < 8; ++i) buf.b[i] = tile[(j * 8 + i) * 68 + cc];
    const int npos = 16 * (j & 3) + 8 * (j >> 2);
    *reinterpret_cast<uint64_t*>(St + (size_t)(c0 + cc) * NN + r0 + npos) = buf.w;
  }
}

// ---------------------------------------------------------------------------
// pack_x0 (gconv 2 only, useR=1): X0t[j][n] = concat(inputs, r*hx)
// ALSO writes xcat m=0 slice (bf16, cols 0..65).  Paired u16 X0t stores.
// ---------------------------------------------------------------------------
__global__ __launch_bounds__(256) void pack_x0(const float* __restrict__ inputs,
                                               const float* __restrict__ hx,
                                               const u16* __restrict__ ru,
                                               u8* __restrict__ X0t,
                                               u16* __restrict__ xcat) {
  __shared__ u16 tile[128 * 76];
  const int n0 = blockIdx.x * 128;
  const int b = blockIdx.y;
  const int t = threadIdx.x;
#pragma unroll
  for (int p = 0; p < 8; ++p) {
    const int idx = p * 256 + t;
    const int n = idx >> 4;
    const int u4 = (idx & 15) * 4;
    float4 v = *reinterpret_cast<const float4*>(
        hx + (size_t)b * (NN * 64) + (size_t)(n0 + n) * 64 + u4);
    ushort4 rv = *reinterpret_cast<const ushort4*>(
        ru + ((size_t)b * NN + n0 + n) * 128 + u4);
    v.x *= bf2f(rv.x); v.y *= bf2f(rv.y); v.z *= bf2f(rv.z); v.w *= bf2f(rv.w);
    ushort4 o;
    o.x = f2bf(v.x); o.y = f2bf(v.y); o.z = f2bf(v.z); o.w = f2bf(v.w);
    *reinterpret_cast<ushort4*>(&tile[n * 76 + u4]) = o;
  }
  __syncthreads();
  // X0t fp8 (transposed, k-packed in n) — paired u16 stores (66*64 = 4224)
#pragma unroll
  for (int p = 0; p < 17; ++p) {
    const int idx = p * 256 + t;
    if (idx < 66 * 64) {
      const int c = idx >> 6;
      const int n = (idx & 63) * 2;      // even n; pair (n, n+1)
      float v0, v1;
      if (c < 2) {
        v0 = inputs[(size_t)b * (NN * 2) + (size_t)(n0 + n) * 2 + c];
        v1 = inputs[(size_t)b * (NN * 2) + (size_t)(n0 + n + 1) * 2 + c];
      } else {
        v0 = bf2f(tile[n * 76 + (c - 2)]);
        v1 = bf2f(tile[(n + 1) * 76 + (c - 2)]);
      }
      const int np = (n & ~63) + kperm(n & 63);   // even; kperm(n+1)=np+1
      const u16 w = (u16)f2e4m3(v0) | ((u16)f2e4m3(v1) << 8);
      *reinterpret_cast<u16*>(
          &X0t[(size_t)(b * CC + c) * NN + n0 + np]) = w;
    }
  }
  // xcat m=0 slice (bf16)
#pragma unroll
  for (int p = 0; p < 17; ++p) {
    const int idx = p * 256 + t;
    if (idx < 128 * 33) {
      const int n = idx / 33;
      const int pr = idx - n * 33;
      const int col = pr * 2;
      u16 v0, v1;
      if (col == 0) {
        v0 = f2bf(inputs[(size_t)b * (NN * 2) + (size_t)(n0 + n) * 2 + 0]);
        v1 = f2bf(inputs[(size_t)b * (NN * 2) + (size_t)(n0 + n) * 2 + 1]);
      } else {
        v0 = tile[n * 76 + (col - 2)];
        v1 = tile[n * 76 + (col - 1)];
      }
      ushort2 o2; o2.x = v0; o2.y = v1;
      *reinterpret_cast<ushort2*>(
          xcat + ((size_t)b * NN + n0 + n) * KF + col) = o2;
    }
  }
}

// new_state = u*hx + (1-u)*c   (vectorized — 4 elems/thread)
__global__ __launch_bounds__(256) void final_k(const float* __restrict__ hx,
                                               const u16* __restrict__ ru,
                                               const u16* __restrict__ cd,
                                               float* __restrict__ out) {
  size_t i = (size_t)blockIdx.x * 256 + threadIdx.x;   // 4 elems each
  size_t s = i >> 4;
  int u4 = (int)(i & 15) * 4;
  float4 h = *reinterpret_cast<const float4*>(&hx[s * 64 + u4]);
  ushort4 uu = *reinterpret_cast<const ushort4*>(&ru[s * 128 + 64 + u4]);
  ushort4 cc = *reinterpret_cast<const ushort4*>(&cd[s * 64 + u4]);
  float4 o;
  float ug;
  ug = bf2f(uu.x); o.x = ug * h.x + (1.0f - ug) * bf2f(cc.x);
  ug = bf2f(uu.y); o.y = ug * h.y + (1.0f - ug) * bf2f(cc.y);
  ug = bf2f(uu.z); o.z = ug * h.z + (1.0f - ug) * bf2f(cc.z);
  ug = bf2f(uu.w); o.w = ug * h.w + (1.0f - ug) * bf2f(cc.w);
  *reinterpret_cast<float4*>(&out[s * 64 + u4]) = o;
}

extern "C" void kernel_launch(void* const* d_in, const int* in_sizes, int n_in,
                              void* d_out, int out_size, void* d_ws, size_t ws_size,
                              hipStream_t stream) {
  const float* inputs = (const float*)d_in[0];
  const float* hx     = (const float*)d_in[1];
  const float* S0     = (const float*)d_in[2];
  const float* S1     = (const float*)d_in[3];
  const float* Wru    = (const float*)d_in[4];
  const float* bru    = (const float*)d_in[5];
  const float* Wc     = (const float*)d_in[6];
  const float* bc     = (const float*)d_in[7];
  float* out = (float*)d_out;

  // workspace layout (~84 MB)
  u8* ws8 = (u8*)d_ws;
  u8* S0h = ws8;                                   // [2048][2048] fp8 (x2^8, k-packed)
  u8* S1h = S0h + (size_t)NN * NN;
  u8* X0t = S1h + (size_t)NN * NN;                 // [JR][2048] fp8 k-packed
  u16* xcat = (u16*)(X0t + (size_t)JR * NN);       // [65536][352] bf16
  u16* Wtru = xcat + (size_t)SROWS * KF;           // [128][352]
  u16* Wtc  = Wtru + (size_t)128 * KF;
  u16* ru   = Wtc + (size_t)128 * KF;              // [65536][128]
  u16* cd   = ru + (size_t)SROWS * 128;            // [65536][64]
  // transient aliases:
  // S0t/S1t live in cd's space (exactly 8MB; cd is dead until dense<3>).
  u8* S0t = (u8*)cd;                               // S^T fp8 k-packed
  u8* S1t = S0t + (size_t)NN * NN;
  u8* T0 = (u8*)d_out;                             // 2S^2-I fp8 (x2^8, k-packed) in d_out
  u8* T1 = T0 + (size_t)NN * NN;                   // (8MB of 16.78; final_k rewrites)

  dim3 b256(256);
  dim3 b512(512);
  // merged cvt_S (y<32) + build_wt (y==32) + pack_x0 #1 (y in [33,41))
  prep<<<dim3(NN / 64, NN / 64 + 9, 2), b256, 0, stream>>>(
      S0, S1, S0h, S1h, S0t, S1t, Wru, Wc, Wtru, Wtc,
      inputs, hx, X0t, xcat);

  // T = 2*S*S - I (fp8 out, x2^8, k-packed): 128x128 tiles, 16x16x2 = 512 blocks
  gemm_f8T<<<dim3(NN / 128, NN / 128, 2), b512, 0, stream>>>(
      S0h, S1h, S0t, S1t, T0, T1, NN, NN, NN, NN);

  // 16 x 8 x 4 = 512 blocks; leftover 64 j-rows folded into mb<4 slivers.
  const dim3 gdiff(16, NN / 256, 4);
  const dim3 gdense(SROWS / 128);            // 512 blocks
  const dim3 gpx0(NN / 128, BB);

  // ---- gconv 1 ----  (pack #1 already done inside prep)
  gemm_f8<5><<<gdiff, b512, 0, stream>>>(
      X0t, X0t, X0t, X0t,  S0h, T0, S1h, T1,
      (void*)xcat, (void*)xcat, (void*)xcat, (void*)xcat,
      NN, NN, NN, KF, JREAL);
  gemm_dense<2><<<gdense, b256, 0, stream>>>(xcat, Wtru, ru, bru, KF, KF, KF, 128, 128);

  // ---- gconv 2 ----
  pack_x0<<<gpx0, b256, 0, stream>>>(inputs, hx, ru, X0t, xcat);
  gemm_f8<5><<<gdiff, b512, 0, stream>>>(
      X0t, X0t, X0t, X0t,  S0h, T0, S1h, T1,
      (void*)xcat, (void*)xcat, (void*)xcat, (void*)xcat,
      NN, NN, NN, KF, JREAL);
  // dense<3> writes cd (overwrites the long-dead S0t/S1t)
  gemm_dense<3><<<gdense, b256, 0, stream>>>(xcat, Wtc, cd, bc, KF, KF, KF, 64, 64);

  // ---- combine (vectorized) ----
  final_k<<<dim3(SROWS * 64 / 1024), b256, 0, stream>>>(hx, ru, cd, out);
}